// Round 5
// baseline (993.002 us; speedup 1.0000x reference)
//
#include <hip/hip_runtime.h>
#include <hip/hip_bf16.h>

// Problem constants
#define BB 16
#define LL 1024
#define DD 384
#define FF 1536
#define KK 3
#define T_OUT 10240
#define MAX_DUR 10

#define PADL 1026                 // per-batch padded rows: [0]=zero, [1..1024]=data, [1025]=zero
#define LO_SCALE 2048.0f          // 2^11: keeps lo parts out of fp16-denormal range
#define LO_INV   4.8828125e-4f    // 2^-11

typedef _Float16 f16x8 __attribute__((ext_vector_type(8)));
typedef float    f32x4 __attribute__((ext_vector_type(4)));

__device__ __forceinline__ void gll16(const void* g, void* l) {
    __builtin_amdgcn_global_load_lds(
        (const __attribute__((address_space(1))) void*)g,
        (__attribute__((address_space(3))) void*)l, 16, 0, 0);
}

__device__ __forceinline__ void split_write(float v, _Float16* hi, _Float16* lo, size_t off) {
    _Float16 h = (_Float16)v;
    hi[off] = h;
    lo[off] = (_Float16)((v - (float)h) * LO_SCALE);
}

__device__ __forceinline__ float split_read(const _Float16* hi, const _Float16* lo, size_t off) {
    return (float)hi[off] + (float)lo[off] * LO_INV;
}

// ---- weight pack: (O,I,3) -> MFMA-fragment-major hi/lo --------------------
// frag layout: [o_tile][ktl][lane][e8], 8 halfs per lane (16 B), so a wave's
// b-frag load is base + lane*16 (one coalesced global_load_dwordx4).
// ktl ordering matches the GEMM k-loop: kseg = ktl%3 (fastest), d0 = (ktl/3)*32.
// lane: n_local = lane&15, k-quad = lane>>4; elem e: koff = kq*8 + e.
__global__ void wfrag_k(const float* __restrict__ w, _Float16* __restrict__ hi,
                        _Float16* __restrict__ lo, int O, int I) {
    int id = blockIdx.x * 256 + threadIdx.x;
    int total = O * 3 * I;
    if (id >= total) return;
    int e = id & 7;
    int lane = (id >> 3) & 63;
    int rest = id >> 9;              // o_tile * nKT + ktl
    int nKT = (3 * I) >> 5;
    int ktl = rest % nKT;
    int ot = rest / nKT;
    int o = ot * 16 + (lane & 15);
    int koff = ((lane >> 4) << 3) + e;
    int kseg = ktl % 3;
    int i = (ktl / 3) * 32 + koff;
    float v = w[(o * I + i) * 3 + kseg];
    split_write(v, hi, lo, id);
}

// ---------------- y split into padded hi/lo layout ---------------------------
__global__ void ysplit_k(const float* __restrict__ y, _Float16* __restrict__ hi,
                         _Float16* __restrict__ lo) {
    int id = blockIdx.x * 256 + threadIdx.x;     // BB*PADL*DD
    if (id >= BB * PADL * DD) return;
    int d = id % DD;
    int r = id / DD;
    int b = r / PADL;
    int lr = r - b * PADL;
    float v = 0.f;
    if (lr >= 1 && lr <= LL) v = y[((size_t)(b << 10) + (lr - 1)) * DD + d];
    split_write(v, hi, lo, id);
}

// ---------------- zero the halo pad rows of a padded split buffer ------------
__global__ void padzero_k(_Float16* __restrict__ hi, _Float16* __restrict__ lo, int width) {
    int id = blockIdx.x * 256 + threadIdx.x;     // BB*2*width
    if (id >= BB * 2 * width) return;
    int b = id / (2 * width);
    int rem = id - b * 2 * width;
    int row = (rem / width) ? (PADL - 1) : 0;
    int c = rem % width;
    size_t off = (size_t)(b * PADL + row) * width + c;
    hi[off] = (_Float16)0.f;
    lo[off] = (_Float16)0.f;
}

// ---------------- split-fp16 MFMA conv-GEMM ----------------------------------
// Round-5: same schedule as round-4 (proven-correct vmcnt ledger), but ALL
// problem dims are template constants (CIN/COUT/KTOT/NN). Round-4 PMC showed
// VALUBusy 36% with MfmaUtil stuck at 53%: runtime dims force per-phase
// v_mul/mad_u64 address chains that re-evaluate inside the k-loop and can't
// fold to SALU. With constexpr dims + j-invariant read offsets hoisted, the
// per-phase VALU collapses to a few adds.
//  * A staged once per d0 super-tile ((BM+2) rows, conv taps share via
//    row+kseg reads); B staged per k-tile (BN cols, unique, frag-major).
//  * 3 phases per super-tile; both LDS buffers double-buffered; counted
//    vmcnt with sched_barrier-pinned issue order:
//      phase s=0: keep NB (B(kt+1));  s=1,2: keep NA+NB.
template<int MI, int BN, int OCC, int CIN, int COUT, int KTOT, int NN>
__global__ __launch_bounds__(256, OCC) void gemm_split(
        const _Float16* __restrict__ Ahi, const _Float16* __restrict__ Alo,
        const _Float16* __restrict__ WfH, const _Float16* __restrict__ WfL,
        const float* __restrict__ bias,
        _Float16* __restrict__ Ohi, _Float16* __restrict__ Olo) {
    constexpr int BM   = MI * 32;            // block M-rows (128)
    constexpr int AC   = (BM + 2) * 4;       // A 16B-chunks per comp (520)
    constexpr int AC4  = AC / 4;             // per-wave A chunks (130)
    constexpr int AIT  = (AC4 + 63) / 64;    // stage iters (3)
    constexpr int NA   = 2 * AIT;            // A gll16 per wave per stage (6)
    constexpr int AHH  = AC * 8;             // halfs per comp
    constexpr int ABH  = 4 * AHH;            // A region halfs (2 bufs x 2 comps)
    constexpr int SEGS = BN / 16;            // 16-col segs per B tile (4)
    constexpr int QS   = SEGS / 4;           // segs per wave (1)
    constexpr int NB   = 2 * QS;             // B gll16 per wave per stage (2)
    constexpr int JJ   = BN / 32;            // col frags per wave (2)
    constexpr int BBH  = 2 * BN * 32;        // halfs per B buffer (4096)
    constexpr int KEEP0  = NB;               // vmcnt keep at phase s=0
    constexpr int KEEP12 = NA + NB;          // vmcnt keep at phases s=1,2
    constexpr int nKT = KTOT >> 5;
    constexpr int nJ  = nKT / 3;             // super-tiles (one per d0 group)
    __shared__ __align__(16) _Float16 lds_h[ABH + 2 * BBH];  // A dbuf | B dbuf
    const int tid = threadIdx.x;
    const int lane = tid & 63;
    const int w = tid >> 6;
    const int lm = lane & 15, lq = lane >> 4;
    // XCD-aware remap: group-of-4 m-tiles, n fastest inside the group
    const int xcd = blockIdx.x & 7;
    const int t2 = blockIdx.x >> 3;
    const int g  = t2 / (4 * NN);
    const int r  = t2 - g * (4 * NN);
    const int n_t = r >> 2;
    const int mi  = r & 3;
    const int m_t = ((g * 4 + mi) << 3) + xcd;
    const int m0 = m_t * BM;
    const int n0 = n_t * BN;
    const int b = m0 >> 10;
    const int l0 = m0 & 1023;
    const int rowBase = b * PADL + l0;           // padded source row of tap -1
    const int wm = (w >> 1) * (MI * 16), wn = (w & 1) * (BN / 2);

    f32x4 accM[MI][JJ], accC[MI][JJ];
    const f32x4 zz = {0.f, 0.f, 0.f, 0.f};
    #pragma unroll
    for (int i = 0; i < MI; ++i)
        #pragma unroll
        for (int jj = 0; jj < JJ; ++jj) { accM[i][jj] = zz; accC[i][jj] = zz; }

    // ---- j-invariant per-lane offsets, computed once -----------------------
    // stage A: global row*CIN + k8*8 per it (add d0 per stage); LDS dest const
    int aRowK[AIT];
    bool aAct[AIT];
    #pragma unroll
    for (int it = 0; it < AIT; ++it) {
        int cl = it * 64 + lane;                 // chunk within wave's range
        int s  = w * AC4 + cl;                   // global chunk id
        int p = s >> 3, sl = s & 7;
        int t = sl ^ (p & 7);
        int m = p * 2 + (t >> 2);
        int k8 = t & 3;
        aRowK[it] = (rowBase + m) * CIN + k8 * 8;
        aAct[it] = (cl < AC4);
    }
    // stage B: per-q global frag base (add ktc*512 per stage)
    int bBase[QS];
    #pragma unroll
    for (int q = 0; q < QS; ++q) {
        int ntg = (n0 >> 4) + w * QS + q;
        bBase[q] = (ntg * nKT * 64 + lane) * 8;
    }

    // stage A super-tile jt ((BM+2) rows x 32 halfs x 2 comps) into buffer bidx
    auto stageA = [&](int jt, int bidx) {
        int d0 = jt << 5;
        _Float16* abase = lds_h + bidx * (2 * AHH);
        #pragma unroll
        for (int it = 0; it < AIT; ++it) {
            size_t aoff = (size_t)(unsigned)(aRowK[it] + d0);
            _Float16* hb = abase + (w * AC4 + it * 64) * 8;  // wave-uniform
            if (aAct[it]) {                      // >=2 lanes active: uniform vmcnt
                gll16(Ahi + aoff, hb);
                gll16(Alo + aoff, hb + AHH);
            }
        }
    };

    // stage B k-tile kt (SEGS segs x 2 comps) into buffer bidx
    auto stageB = [&](int kt, int bidx) {
        int ktc = kt < nKT ? kt : nKT - 1;
        _Float16* bb = lds_h + ABH + bidx * BBH;
        #pragma unroll
        for (int q = 0; q < QS; ++q) {
            int sg = w * QS + q;
            size_t boff = (size_t)(unsigned)(bBase[q] + ktc * 512);
            gll16(WfH + boff, bb + sg * 512);
            gll16(WfL + boff, bb + BN * 32 + sg * 512);
        }
    };

    // MFMA phase: A frags from ab (+kseg row shift), B frags from bb.
    // kseg is a literal at every call site -> all offsets compile-time folded.
    auto compute = [&](const _Float16* ab, const _Float16* bb, int kseg) {
        f16x8 bH[JJ], bL[JJ];
        #pragma unroll
        for (int jj = 0; jj < JJ; ++jj) {
            int nl = (w & 1) * JJ + jj;
            bH[jj] = *(const f16x8*)(bb + nl * 512 + lane * 8);
            bL[jj] = *(const f16x8*)(bb + BN * 32 + nl * 512 + lane * 8);
        }
        __builtin_amdgcn_s_setprio(1);
        #pragma unroll
        for (int i = 0; i < MI; ++i) {
            int row = wm + i * 16 + lm + kseg;
            int p = row >> 1;
            int sl = (((row & 1) << 2) | lq) ^ (p & 7);
            int off = p * 64 + sl * 8;
            f16x8 aH = *(const f16x8*)(ab + off);
            f16x8 aL = *(const f16x8*)(ab + AHH + off);
            #pragma unroll
            for (int jj = 0; jj < JJ; ++jj) {
                accM[i][jj] = __builtin_amdgcn_mfma_f32_16x16x32_f16(aH, bH[jj], accM[i][jj], 0, 0, 0);
                accC[i][jj] = __builtin_amdgcn_mfma_f32_16x16x32_f16(aH, bL[jj], accC[i][jj], 0, 0, 0);
                accC[i][jj] = __builtin_amdgcn_mfma_f32_16x16x32_f16(aL, bH[jj], accC[i][jj], 0, 0, 0);
            }
        }
        __builtin_amdgcn_s_setprio(0);
    };

    // prologue: B(0)->b0, A(0)->a0, B(1)->b1 (issue order pinned for vmcnt math)
    stageB(0, 0);
    __builtin_amdgcn_sched_barrier(0);
    stageA(0, 0);
    __builtin_amdgcn_sched_barrier(0);
    stageB(1, 1);
    __builtin_amdgcn_sched_barrier(0);

    for (int j = 0; j < nJ; ++j) {
        const _Float16* ab = lds_h + (j & 1) * (2 * AHH);
        const int kt = 3 * j;
        // ---- phase s=0: compute kt, then stage B(kt+2) + A(j+1) ----------
        asm volatile("s_waitcnt vmcnt(%0)" :: "i"(KEEP0) : "memory");
        __builtin_amdgcn_s_barrier();
        __builtin_amdgcn_sched_barrier(0);
        compute(ab, lds_h + ABH + (kt & 1) * BBH, 0);
        __builtin_amdgcn_sched_barrier(0);
        __builtin_amdgcn_s_barrier();
        stageB(kt + 2, kt & 1);                    // overwrite just-read buffer
        __builtin_amdgcn_sched_barrier(0);
        stageA(j + 1 < nJ ? j + 1 : j, (j + 1) & 1);
        __builtin_amdgcn_sched_barrier(0);
        // ---- phase s=1 ----------------------------------------------------
        asm volatile("s_waitcnt vmcnt(%0)" :: "i"(KEEP12) : "memory");
        __builtin_amdgcn_s_barrier();
        __builtin_amdgcn_sched_barrier(0);
        compute(ab, lds_h + ABH + ((kt + 1) & 1) * BBH, 1);
        __builtin_amdgcn_sched_barrier(0);
        __builtin_amdgcn_s_barrier();
        stageB(kt + 3, (kt + 1) & 1);
        __builtin_amdgcn_sched_barrier(0);
        // ---- phase s=2 ----------------------------------------------------
        asm volatile("s_waitcnt vmcnt(%0)" :: "i"(KEEP12) : "memory");
        __builtin_amdgcn_s_barrier();
        __builtin_amdgcn_sched_barrier(0);
        compute(ab, lds_h + ABH + (kt & 1) * BBH, 2);
        __builtin_amdgcn_sched_barrier(0);
        __builtin_amdgcn_s_barrier();
        stageB(kt + 4, kt & 1);
        __builtin_amdgcn_sched_barrier(0);
    }
    // epilogue: bias + relu + re-split to padded hi/lo output
    #pragma unroll
    for (int i = 0; i < MI; ++i)
        #pragma unroll
        for (int jj = 0; jj < JJ; ++jj) {
            int n_g = n0 + wn + jj * 16 + lm;
            float bv = bias[n_g];
            #pragma unroll
            for (int rr = 0; rr < 4; ++rr) {
                int l = l0 + wm + i * 16 + lq * 4 + rr;
                float v = accM[i][jj][rr] + accC[i][jj][rr] * LO_INV + bv;
                v = fmaxf(v, 0.f);
                size_t off = (size_t)(b * PADL + 1 + l) * COUT + n_g;
                split_write(v, Ohi, Olo, off);
            }
        }
}

// ---------------- layernorm in place on split buffer (width 384) -------------
__global__ __launch_bounds__(128) void ln_split_k(
        _Float16* __restrict__ hi, _Float16* __restrict__ lo,
        const float* __restrict__ g, const float* __restrict__ be) {
    const int row = blockIdx.x;
    const int b = row >> 10, l = row & 1023;
    const size_t base = (size_t)(b * PADL + 1 + l) * DD;
    const int tid = threadIdx.x;
    float v0 = split_read(hi, lo, base + tid);
    float v1 = split_read(hi, lo, base + tid + 128);
    float v2 = split_read(hi, lo, base + tid + 256);

    __shared__ float sh[2];
    float s = v0 + v1 + v2;
    #pragma unroll
    for (int o = 32; o > 0; o >>= 1) s += __shfl_down(s, o, 64);
    if ((tid & 63) == 0) sh[tid >> 6] = s;
    __syncthreads();
    float mu = (sh[0] + sh[1]) * (1.f / DD);
    __syncthreads();
    float d0 = v0 - mu, d1 = v1 - mu, d2 = v2 - mu;
    float q = d0 * d0 + d1 * d1 + d2 * d2;
    #pragma unroll
    for (int o = 32; o > 0; o >>= 1) q += __shfl_down(q, o, 64);
    if ((tid & 63) == 0) sh[tid >> 6] = q;
    __syncthreads();
    float var = (sh[0] + sh[1]) * (1.f / DD);
    float rs = rsqrtf(var + 1e-5f);
    split_write(d0 * rs * g[tid] + be[tid], hi, lo, base + tid);
    split_write(d1 * rs * g[tid + 128] + be[tid + 128], hi, lo, base + tid + 128);
    split_write(d2 * rs * g[tid + 256] + be[tid + 256], hi, lo, base + tid + 256);
}

// ---------------- layernorm + length predictor on split buffer ---------------
__global__ __launch_bounds__(128) void ln_pred_split_k(
        const _Float16* __restrict__ hi, const _Float16* __restrict__ lo,
        const float* __restrict__ g, const float* __restrict__ be,
        const float* __restrict__ wl, const float* __restrict__ bl,
        const int* __restrict__ token_lengths, int* __restrict__ lns) {
    const int row = blockIdx.x;
    const int b = row >> 10, l = row & 1023;
    const size_t base = (size_t)(b * PADL + 1 + l) * DD;
    const int tid = threadIdx.x;
    float v0 = split_read(hi, lo, base + tid);
    float v1 = split_read(hi, lo, base + tid + 128);
    float v2 = split_read(hi, lo, base + tid + 256);

    __shared__ float sh[2];
    float s = v0 + v1 + v2;
    #pragma unroll
    for (int o = 32; o > 0; o >>= 1) s += __shfl_down(s, o, 64);
    if ((tid & 63) == 0) sh[tid >> 6] = s;
    __syncthreads();
    float mu = (sh[0] + sh[1]) * (1.f / DD);
    __syncthreads();
    float d0 = v0 - mu, d1 = v1 - mu, d2 = v2 - mu;
    float q = d0 * d0 + d1 * d1 + d2 * d2;
    #pragma unroll
    for (int o = 32; o > 0; o >>= 1) q += __shfl_down(q, o, 64);
    if ((tid & 63) == 0) sh[tid >> 6] = q;
    __syncthreads();
    float var = (sh[0] + sh[1]) * (1.f / DD);
    float rs = rsqrtf(var + 1e-5f);
    __syncthreads();
    float p = (d0 * rs * g[tid]       + be[tid])       * wl[tid]
            + (d1 * rs * g[tid + 128] + be[tid + 128]) * wl[tid + 128]
            + (d2 * rs * g[tid + 256] + be[tid + 256]) * wl[tid + 256];
    #pragma unroll
    for (int o = 32; o > 0; o >>= 1) p += __shfl_down(p, o, 64);
    if ((tid & 63) == 0) sh[tid >> 6] = p;
    __syncthreads();
    if (tid == 0) {
        float pred = sh[0] + sh[1] + bl[0];
        float e = expf(pred);           // ALPHA == 1.0
        float r = rintf(e);             // round-half-even, matches jnp.round
        r = fminf(fmaxf(r, 0.f), (float)MAX_DUR);
        int v = (int)r;
        if (l >= token_lengths[b]) v = 0;
        lns[row] = v;
    }
}

// ---------------- per-batch inclusive cumsum (L=1024) ------------------------
__global__ __launch_bounds__(1024) void cumsum_k(
        const int* __restrict__ lns, int* __restrict__ csum,
        float* __restrict__ totals_out) {
    __shared__ int s[1024];
    const int b = blockIdx.x, tid = threadIdx.x;
    s[tid] = lns[(b << 10) + tid];
    __syncthreads();
    #pragma unroll
    for (int o = 1; o < 1024; o <<= 1) {
        int t = (tid >= o) ? s[tid - o] : 0;
        __syncthreads();
        s[tid] += t;
        __syncthreads();
    }
    csum[(b << 10) + tid] = s[tid];
    if (tid == 1023) totals_out[b] = (float)s[1023];
}

// ---------------- gather: out[b,t,:] = valid ? y[b, idx(t), :] : 0 -----------
__global__ __launch_bounds__(256) void gather_k(
        const float* __restrict__ y, const int* __restrict__ csum,
        float* __restrict__ out) {
    int gid = blockIdx.x * 256 + threadIdx.x;   // B*T_OUT*96 float4 chunks
    int c4 = gid % 96;
    int rest = gid / 96;
    int t = rest % T_OUT;
    int b = rest / T_OUT;
    const int* c = csum + (b << 10);
    int total = c[1023];
    float4 r = make_float4(0.f, 0.f, 0.f, 0.f);
    if (t < total) {
        int lo = 0, hi = 1024;
        while (lo < hi) {               // searchsorted side='right'
            int mid = (lo + hi) >> 1;
            if (c[mid] <= t) lo = mid + 1; else hi = mid;
        }
        int idx = min(lo, LL - 1);
        r = *(const float4*)(y + ((size_t)((b << 10) + idx)) * DD + (c4 << 2));
    }
    *(float4*)(out + ((size_t)b * T_OUT + t) * DD + (c4 << 2)) = r;
}

// ---------------- host side --------------------------------------------------
extern "C" void kernel_launch(void* const* d_in, const int* in_sizes, int n_in,
                              void* d_out, int out_size, void* d_ws, size_t ws_size,
                              hipStream_t stream) {
    const float* y   = (const float*)d_in[0];
    const int*   tok = (const int*)d_in[1];
    const float* w1a = (const float*)d_in[2];
    const float* b1a = (const float*)d_in[3];
    const float* w1b = (const float*)d_in[4];
    const float* b1b = (const float*)d_in[5];
    const float* g1  = (const float*)d_in[6];
    const float* be1 = (const float*)d_in[7];
    const float* w2a = (const float*)d_in[8];
    const float* b2a = (const float*)d_in[9];
    const float* w2b = (const float*)d_in[10];
    const float* b2b = (const float*)d_in[11];
    const float* g2  = (const float*)d_in[12];
    const float* be2 = (const float*)d_in[13];
    const float* wl  = (const float*)d_in[14];
    const float* bl  = (const float*)d_in[15];

    float* out = (float*)d_out;

    // workspace layout (halfs)
    const size_t WN   = (size_t)FF * DD * KK;          // 1,769,472 per weight comp
    const size_t SN   = (size_t)BB * PADL * DD;        // 6,303,744
    const size_t H1N  = (size_t)BB * PADL * FF;        // 25,214,976
    _Float16* p = (_Float16*)d_ws;
    _Float16* Wh1a = p;              _Float16* Wl1a = Wh1a + WN;
    _Float16* Wh1b = Wl1a + WN;      _Float16* Wl1b = Wh1b + WN;
    _Float16* Wh2a = Wl1b + WN;      _Float16* Wl2a = Wh2a + WN;
    _Float16* Wh2b = Wl2a + WN;      _Float16* Wl2b = Wh2b + WN;
    _Float16* Shi  = Wl2b + WN;      _Float16* Slo  = Shi + SN;
    _Float16* H1hi = Slo + SN;       _Float16* H1lo = H1hi + H1N;
    int* lns  = (int*)(H1lo + H1N);
    int* csum = lns + BB * LL;

    const int M = BB * LL;                              // 16384

    // 1) weight frag-pack+split, y split, pad-zero for H1
    {
        int n = FF * DD * KK;
        wfrag_k<<<(n + 255) / 256, 256, 0, stream>>>(w1a, Wh1a, Wl1a, FF, DD);
        wfrag_k<<<(n + 255) / 256, 256, 0, stream>>>(w1b, Wh1b, Wl1b, DD, FF);
        wfrag_k<<<(n + 255) / 256, 256, 0, stream>>>(w2a, Wh2a, Wl2a, FF, DD);
        wfrag_k<<<(n + 255) / 256, 256, 0, stream>>>(w2b, Wh2b, Wl2b, DD, FF);
        int ny = BB * PADL * DD;
        ysplit_k<<<(ny + 255) / 256, 256, 0, stream>>>(y, Shi, Slo);
        int np = BB * 2 * FF;
        padzero_k<<<(np + 255) / 256, 256, 0, stream>>>(H1hi, H1lo, FF);
    }
    // 2) four conv-GEMMs (1-D grids, XCD-remapped in-kernel), all MI=4/BN=64,
    //    compile-time dims:
    //    D->F: 24n x 128m = 3072 blocks = 4.0 rounds of 768 slots (3/CU)
    //    F->D:  6n x 128m =  768 blocks = 1.0 round  of 768 slots (3/CU)
    gemm_split<4, 64, 3, DD, FF, 3 * DD, FF / 64>
        <<<(FF / 64) * (M / 128), 256, 0, stream>>>(Shi, Slo, Wh1a, Wl1a, b1a, H1hi, H1lo);
    gemm_split<4, 64, 3, FF, DD, 3 * FF, DD / 64>
        <<<(DD / 64) * (M / 128), 256, 0, stream>>>(H1hi, H1lo, Wh1b, Wl1b, b1b, Shi, Slo);
    ln_split_k<<<M, 128, 0, stream>>>(Shi, Slo, g1, be1);
    gemm_split<4, 64, 3, DD, FF, 3 * DD, FF / 64>
        <<<(FF / 64) * (M / 128), 256, 0, stream>>>(Shi, Slo, Wh2a, Wl2a, b2a, H1hi, H1lo);
    gemm_split<4, 64, 3, FF, DD, 3 * FF, DD / 64>
        <<<(DD / 64) * (M / 128), 256, 0, stream>>>(H1hi, H1lo, Wh2b, Wl2b, b2b, Shi, Slo);
    // 3) predictor + cumsum + gather
    ln_pred_split_k<<<M, 128, 0, stream>>>(Shi, Slo, g2, be2, wl, bl, tok, lns);
    cumsum_k<<<BB, 1024, 0, stream>>>(lns, csum, out + (size_t)BB * T_OUT * DD);
    {
        long long n = (long long)BB * T_OUT * 96;
        gather_k<<<(int)((n + 255) / 256), 256, 0, stream>>>(y, csum, out);
    }
}

// Round 6
// 952.590 us; speedup vs baseline: 1.0424x; 1.0424x over previous
//
#include <hip/hip_runtime.h>
#include <hip/hip_bf16.h>

// Problem constants
#define BB 16
#define LL 1024
#define DD 384
#define FF 1536
#define KK 3
#define T_OUT 10240
#define MAX_DUR 10

#define PADL 1026                 // per-batch padded rows: [0]=zero, [1..1024]=data, [1025]=zero
#define LO_SCALE 2048.0f          // 2^11: keeps lo parts out of fp16-denormal range
#define LO_INV   4.8828125e-4f    // 2^-11

typedef _Float16 f16x8 __attribute__((ext_vector_type(8)));
typedef float    f32x4 __attribute__((ext_vector_type(4)));

__device__ __forceinline__ void gll16(const void* g, void* l) {
    __builtin_amdgcn_global_load_lds(
        (const __attribute__((address_space(1))) void*)g,
        (__attribute__((address_space(3))) void*)l, 16, 0, 0);
}

__device__ __forceinline__ void split_write(float v, _Float16* hi, _Float16* lo, size_t off) {
    _Float16 h = (_Float16)v;
    hi[off] = h;
    lo[off] = (_Float16)((v - (float)h) * LO_SCALE);
}

__device__ __forceinline__ float split_read(const _Float16* hi, const _Float16* lo, size_t off) {
    return (float)hi[off] + (float)lo[off] * LO_INV;
}

// ---- weight pack: (O,I,3) -> MFMA-fragment-major hi/lo --------------------
// frag layout: [o_tile][ktl][lane][e8], 8 halfs per lane (16 B).
// ktl ordering matches the GEMM k-loop: kseg = ktl%3 (fastest), d0 = (ktl/3)*32.
__global__ void wfrag_k(const float* __restrict__ w, _Float16* __restrict__ hi,
                        _Float16* __restrict__ lo, int O, int I) {
    int id = blockIdx.x * 256 + threadIdx.x;
    int total = O * 3 * I;
    if (id >= total) return;
    int e = id & 7;
    int lane = (id >> 3) & 63;
    int rest = id >> 9;              // o_tile * nKT + ktl
    int nKT = (3 * I) >> 5;
    int ktl = rest % nKT;
    int ot = rest / nKT;
    int o = ot * 16 + (lane & 15);
    int koff = ((lane >> 4) << 3) + e;
    int kseg = ktl % 3;
    int i = (ktl / 3) * 32 + koff;
    float v = w[(o * I + i) * 3 + kseg];
    split_write(v, hi, lo, id);
}

// ---------------- y split into padded hi/lo layout ---------------------------
__global__ void ysplit_k(const float* __restrict__ y, _Float16* __restrict__ hi,
                         _Float16* __restrict__ lo) {
    int id = blockIdx.x * 256 + threadIdx.x;     // BB*PADL*DD
    if (id >= BB * PADL * DD) return;
    int d = id % DD;
    int r = id / DD;
    int b = r / PADL;
    int lr = r - b * PADL;
    float v = 0.f;
    if (lr >= 1 && lr <= LL) v = y[((size_t)(b << 10) + (lr - 1)) * DD + d];
    split_write(v, hi, lo, id);
}

// ---------------- zero the halo pad rows of a padded split buffer ------------
__global__ void padzero_k(_Float16* __restrict__ hi, _Float16* __restrict__ lo, int width) {
    int id = blockIdx.x * 256 + threadIdx.x;     // BB*2*width
    if (id >= BB * 2 * width) return;
    int b = id / (2 * width);
    int rem = id - b * 2 * width;
    int row = (rem / width) ? (PADL - 1) : 0;
    int c = rem % width;
    size_t off = (size_t)(b * PADL + row) * width + c;
    hi[off] = (_Float16)0.f;
    lo[off] = (_Float16)0.f;
}

// ---------------- split-fp16 MFMA conv-GEMM, fused super-tile ----------------
// Round-6: the k-loop is LDS-traffic + barrier bound (R3/R4/R5 all plateau at
// ~50% MfmaUtil; per-phase LDS demand ~2260 cyc vs 1398 MFMA cyc). Fuse the 3
// conv-tap phases into ONE compute burst per d0 super-tile:
//  * ALL B fragments for the super-tile (3 ktiles x 3 frags x hi/lo = 18 b128,
//    72 VGPR) are read to registers right after the top barrier; B LDS is then
//    single-buffered (36 KB) and restaged for j+1 DURING the burst.
//  * 2 barriers per super-tile instead of 6; 108 MFMAs per burst.
//  * A stays double-buffered in LDS (33 KB), fragments streamed with a 1-deep
//    register pipeline; conv taps read row+kseg from the same staged tile.
//  * vmcnt(0) at super-tile top only: issue-to-wait distance is a full burst
//    (~4000 cyc), so no m97-style drain stall.
// BN=96: JJ=3, acc=96 VGPR; D->F grid 2048 = 4.0 rounds of 512 (2 blocks/CU),
// F->D 512 = exactly 1.0 round. LDS 70.1 KB/block.
template<int MI, int BN, int CIN, int COUT, int KTOT, int NN>
__global__ __launch_bounds__(256, 2) void gemm_fused(
        const _Float16* __restrict__ Ahi, const _Float16* __restrict__ Alo,
        const _Float16* __restrict__ WfH, const _Float16* __restrict__ WfL,
        const float* __restrict__ bias,
        _Float16* __restrict__ Ohi, _Float16* __restrict__ Olo) {
    constexpr int BM   = MI * 32;            // 128
    constexpr int AC   = (BM + 2) * 4;       // A 16B-chunks per comp (520)
    constexpr int AC4  = AC / 4;             // per-wave chunks (130)
    constexpr int AIT  = (AC4 + 63) / 64;    // stage iters (3)
    constexpr int AHH  = AC * 8;             // halfs per comp (4160)
    constexpr int ABH  = 4 * AHH;            // A region (2 bufs x 2 comps) 16640
    constexpr int SEGS = BN / 16;            // 6
    constexpr int JJ   = BN / 32;            // col frags per wave (3)
    constexpr int BHALF = 3 * SEGS * 512;    // B halfs per comp (9216)
    constexpr int BUNITS = 3 * SEGS;         // 18 seg-units per super-tile
    constexpr int nKT = KTOT >> 5;
    constexpr int nJ  = nKT / 3;
    __shared__ __align__(16) _Float16 lds_h[ABH + 2 * BHALF];  // A dbuf | B single
    const int tid = threadIdx.x;
    const int lane = tid & 63;
    const int w = tid >> 6;
    const int lm = lane & 15, lq = lane >> 4;
    // XCD-aware remap: group-of-4 m-tiles, n fastest inside the group
    const int xcd = blockIdx.x & 7;
    const int t2 = blockIdx.x >> 3;
    const int g  = t2 / (4 * NN);
    const int r  = t2 - g * (4 * NN);
    const int n_t = r >> 2;
    const int mi  = r & 3;
    const int m_t = ((g * 4 + mi) << 3) + xcd;
    const int m0 = m_t * BM;
    const int n0 = n_t * BN;
    const int b = m0 >> 10;
    const int l0 = m0 & 1023;
    const int rowBase = b * PADL + l0;           // padded source row of tap -1
    const int wm = (w >> 1) * (MI * 16), wn = (w & 1) * (BN / 2);

    f32x4 accM[MI][JJ], accC[MI][JJ];
    const f32x4 zz = {0.f, 0.f, 0.f, 0.f};
    #pragma unroll
    for (int i = 0; i < MI; ++i)
        #pragma unroll
        for (int jj = 0; jj < JJ; ++jj) { accM[i][jj] = zz; accC[i][jj] = zz; }

    // ---- j-invariant per-lane offsets ------------------------------------
    // A stage: global row*CIN + k8*8 (add d0 per super-tile)
    int aRowK[AIT];
    bool aAct[AIT];
    #pragma unroll
    for (int it = 0; it < AIT; ++it) {
        int cl = it * 64 + lane;
        int s  = w * AC4 + cl;
        int p = s >> 3, sl = s & 7;
        int t = sl ^ (p & 7);
        int m = p * 2 + (t >> 2);
        int k8 = t & 3;
        aRowK[it] = (rowBase + m) * CIN + k8 * 8;
        aAct[it] = (cl < AC4);
    }
    // B stage: wave w handles units u = w+4t (waves 0,1: 5 units; 2,3: 4)
    int bOffK[5];                      // global half-offset sans jc*1536
    int bDstH[5];                      // LDS half-offset within B region
    bool bActv[5];
    #pragma unroll
    for (int t = 0; t < 5; ++t) {
        int u = w + 4 * t;
        bActv[t] = (u < BUNITS);
        int uc = bActv[t] ? u : 0;
        int s = uc / SEGS, seg = uc % SEGS;
        bOffK[t] = (((n0 >> 4) + seg) * nKT * 64 + lane) * 8 + s * 512;
        bDstH[t] = uc * 512;
    }
    // A compute-frag offsets for t=0..11 (row = wm + (t&3)*16 + lm + (t>>2))
    int aOff[MI * 3];
    #pragma unroll
    for (int t = 0; t < MI * 3; ++t) {
        int row = wm + (t & 3) * 16 + lm + (t >> 2);
        int p = row >> 1;
        int sl = (((row & 1) << 2) | lq) ^ (p & 7);
        aOff[t] = p * 64 + sl * 8;
    }

    auto stageA = [&](int jt, int bidx) {
        int d0 = jt << 5;
        _Float16* abase = lds_h + bidx * (2 * AHH);
        #pragma unroll
        for (int it = 0; it < AIT; ++it) {
            size_t aoff = (size_t)(unsigned)(aRowK[it] + d0);
            _Float16* hb = abase + (w * AC4 + it * 64) * 8;  // wave-uniform
            if (aAct[it]) {
                gll16(Ahi + aoff, hb);
                gll16(Alo + aoff, hb + AHH);
            }
        }
    };

    auto stageB = [&](int jt) {
        int jc = jt < nJ ? jt : nJ - 1;
        _Float16* bb = lds_h + ABH;
        #pragma unroll
        for (int t = 0; t < 5; ++t) {
            if (bActv[t]) {
                size_t boff = (size_t)(unsigned)(bOffK[t] + jc * 1536);
                gll16(WfH + boff, bb + bDstH[t]);
                gll16(WfL + boff, bb + BHALF + bDstH[t]);
            }
        }
    };

    stageB(0);
    stageA(0, 0);

    for (int j = 0; j < nJ; ++j) {
        // ---- top: A(j)+B(j) landed (issued a full super-tile ago) --------
        asm volatile("s_waitcnt vmcnt(0)" ::: "memory");
        __builtin_amdgcn_s_barrier();
        __builtin_amdgcn_sched_barrier(0);
        // ---- B fragments -> registers ------------------------------------
        f16x8 bH[3][JJ], bL[3][JJ];
        {
            const _Float16* bb = lds_h + ABH;
            #pragma unroll
            for (int s = 0; s < 3; ++s)
                #pragma unroll
                for (int jj = 0; jj < JJ; ++jj) {
                    int nl = (w & 1) * JJ + jj;
                    const _Float16* pB = bb + (s * SEGS + nl) * 512 + lane * 8;
                    bH[s][jj] = *(const f16x8*)pB;
                    bL[s][jj] = *(const f16x8*)(pB + BHALF);
                }
        }
        __builtin_amdgcn_sched_barrier(0);
        asm volatile("s_waitcnt lgkmcnt(0)" ::: "memory");
        __builtin_amdgcn_s_barrier();            // all waves' B reads done
        __builtin_amdgcn_sched_barrier(0);
        // ---- restage B (safe now) + A(j+1), loads fly under the burst ----
        stageB(j + 1);
        stageA(j + 1 < nJ ? j + 1 : nJ - 1, (j + 1) & 1);
        __builtin_amdgcn_sched_barrier(0);
        // ---- 108-MFMA burst, A streamed with 1-deep reg pipeline ---------
        const _Float16* ab = lds_h + (j & 1) * (2 * AHH);
        __builtin_amdgcn_s_setprio(1);
        f16x8 aHc = *(const f16x8*)(ab + aOff[0]);
        f16x8 aLc = *(const f16x8*)(ab + AHH + aOff[0]);
        #pragma unroll
        for (int t = 0; t < MI * 3; ++t) {
            f16x8 aHn, aLn;
            if (t < MI * 3 - 1) {
                aHn = *(const f16x8*)(ab + aOff[t + 1]);
                aLn = *(const f16x8*)(ab + AHH + aOff[t + 1]);
            }
            int s = t >> 2, i = t & 3;           // literals after unroll
            #pragma unroll
            for (int jj = 0; jj < JJ; ++jj) {
                accM[i][jj] = __builtin_amdgcn_mfma_f32_16x16x32_f16(aHc, bH[s][jj], accM[i][jj], 0, 0, 0);
                accC[i][jj] = __builtin_amdgcn_mfma_f32_16x16x32_f16(aHc, bL[s][jj], accC[i][jj], 0, 0, 0);
                accC[i][jj] = __builtin_amdgcn_mfma_f32_16x16x32_f16(aLc, bH[s][jj], accC[i][jj], 0, 0, 0);
            }
            aHc = aHn; aLc = aLn;
        }
        __builtin_amdgcn_s_setprio(0);
        __builtin_amdgcn_sched_barrier(0);
    }
    // epilogue: bias + relu + re-split to padded hi/lo output
    #pragma unroll
    for (int i = 0; i < MI; ++i)
        #pragma unroll
        for (int jj = 0; jj < JJ; ++jj) {
            int n_g = n0 + wn + jj * 16 + lm;
            float bv = bias[n_g];
            #pragma unroll
            for (int rr = 0; rr < 4; ++rr) {
                int l = l0 + wm + i * 16 + lq * 4 + rr;
                float v = accM[i][jj][rr] + accC[i][jj][rr] * LO_INV + bv;
                v = fmaxf(v, 0.f);
                size_t off = (size_t)(b * PADL + 1 + l) * COUT + n_g;
                split_write(v, Ohi, Olo, off);
            }
        }
}

// ---------------- layernorm in place on split buffer (width 384) -------------
__global__ __launch_bounds__(128) void ln_split_k(
        _Float16* __restrict__ hi, _Float16* __restrict__ lo,
        const float* __restrict__ g, const float* __restrict__ be) {
    const int row = blockIdx.x;
    const int b = row >> 10, l = row & 1023;
    const size_t base = (size_t)(b * PADL + 1 + l) * DD;
    const int tid = threadIdx.x;
    float v0 = split_read(hi, lo, base + tid);
    float v1 = split_read(hi, lo, base + tid + 128);
    float v2 = split_read(hi, lo, base + tid + 256);

    __shared__ float sh[2];
    float s = v0 + v1 + v2;
    #pragma unroll
    for (int o = 32; o > 0; o >>= 1) s += __shfl_down(s, o, 64);
    if ((tid & 63) == 0) sh[tid >> 6] = s;
    __syncthreads();
    float mu = (sh[0] + sh[1]) * (1.f / DD);
    __syncthreads();
    float d0 = v0 - mu, d1 = v1 - mu, d2 = v2 - mu;
    float q = d0 * d0 + d1 * d1 + d2 * d2;
    #pragma unroll
    for (int o = 32; o > 0; o >>= 1) q += __shfl_down(q, o, 64);
    if ((tid & 63) == 0) sh[tid >> 6] = q;
    __syncthreads();
    float var = (sh[0] + sh[1]) * (1.f / DD);
    float rs = rsqrtf(var + 1e-5f);
    split_write(d0 * rs * g[tid] + be[tid], hi, lo, base + tid);
    split_write(d1 * rs * g[tid + 128] + be[tid + 128], hi, lo, base + tid + 128);
    split_write(d2 * rs * g[tid + 256] + be[tid + 256], hi, lo, base + tid + 256);
}

// ---------------- layernorm + length predictor on split buffer ---------------
__global__ __launch_bounds__(128) void ln_pred_split_k(
        const _Float16* __restrict__ hi, const _Float16* __restrict__ lo,
        const float* __restrict__ g, const float* __restrict__ be,
        const float* __restrict__ wl, const float* __restrict__ bl,
        const int* __restrict__ token_lengths, int* __restrict__ lns) {
    const int row = blockIdx.x;
    const int b = row >> 10, l = row & 1023;
    const size_t base = (size_t)(b * PADL + 1 + l) * DD;
    const int tid = threadIdx.x;
    float v0 = split_read(hi, lo, base + tid);
    float v1 = split_read(hi, lo, base + tid + 128);
    float v2 = split_read(hi, lo, base + tid + 256);

    __shared__ float sh[2];
    float s = v0 + v1 + v2;
    #pragma unroll
    for (int o = 32; o > 0; o >>= 1) s += __shfl_down(s, o, 64);
    if ((tid & 63) == 0) sh[tid >> 6] = s;
    __syncthreads();
    float mu = (sh[0] + sh[1]) * (1.f / DD);
    __syncthreads();
    float d0 = v0 - mu, d1 = v1 - mu, d2 = v2 - mu;
    float q = d0 * d0 + d1 * d1 + d2 * d2;
    #pragma unroll
    for (int o = 32; o > 0; o >>= 1) q += __shfl_down(q, o, 64);
    if ((tid & 63) == 0) sh[tid >> 6] = q;
    __syncthreads();
    float var = (sh[0] + sh[1]) * (1.f / DD);
    float rs = rsqrtf(var + 1e-5f);
    __syncthreads();
    float p = (d0 * rs * g[tid]       + be[tid])       * wl[tid]
            + (d1 * rs * g[tid + 128] + be[tid + 128]) * wl[tid + 128]
            + (d2 * rs * g[tid + 256] + be[tid + 256]) * wl[tid + 256];
    #pragma unroll
    for (int o = 32; o > 0; o >>= 1) p += __shfl_down(p, o, 64);
    if ((tid & 63) == 0) sh[tid >> 6] = p;
    __syncthreads();
    if (tid == 0) {
        float pred = sh[0] + sh[1] + bl[0];
        float e = expf(pred);           // ALPHA == 1.0
        float r = rintf(e);             // round-half-even, matches jnp.round
        r = fminf(fmaxf(r, 0.f), (float)MAX_DUR);
        int v = (int)r;
        if (l >= token_lengths[b]) v = 0;
        lns[row] = v;
    }
}

// ---------------- per-batch inclusive cumsum (L=1024) ------------------------
__global__ __launch_bounds__(1024) void cumsum_k(
        const int* __restrict__ lns, int* __restrict__ csum,
        float* __restrict__ totals_out) {
    __shared__ int s[1024];
    const int b = blockIdx.x, tid = threadIdx.x;
    s[tid] = lns[(b << 10) + tid];
    __syncthreads();
    #pragma unroll
    for (int o = 1; o < 1024; o <<= 1) {
        int t = (tid >= o) ? s[tid - o] : 0;
        __syncthreads();
        s[tid] += t;
        __syncthreads();
    }
    csum[(b << 10) + tid] = s[tid];
    if (tid == 1023) totals_out[b] = (float)s[1023];
}

// ---------------- gather: out[b,t,:] = valid ? y[b, idx(t), :] : 0 -----------
__global__ __launch_bounds__(256) void gather_k(
        const float* __restrict__ y, const int* __restrict__ csum,
        float* __restrict__ out) {
    int gid = blockIdx.x * 256 + threadIdx.x;   // B*T_OUT*96 float4 chunks
    int c4 = gid % 96;
    int rest = gid / 96;
    int t = rest % T_OUT;
    int b = rest / T_OUT;
    const int* c = csum + (b << 10);
    int total = c[1023];
    float4 r = make_float4(0.f, 0.f, 0.f, 0.f);
    if (t < total) {
        int lo = 0, hi = 1024;
        while (lo < hi) {               // searchsorted side='right'
            int mid = (lo + hi) >> 1;
            if (c[mid] <= t) lo = mid + 1; else hi = mid;
        }
        int idx = min(lo, LL - 1);
        r = *(const float4*)(y + ((size_t)((b << 10) + idx)) * DD + (c4 << 2));
    }
    *(float4*)(out + ((size_t)b * T_OUT + t) * DD + (c4 << 2)) = r;
}

// ---------------- host side --------------------------------------------------
extern "C" void kernel_launch(void* const* d_in, const int* in_sizes, int n_in,
                              void* d_out, int out_size, void* d_ws, size_t ws_size,
                              hipStream_t stream) {
    const float* y   = (const float*)d_in[0];
    const int*   tok = (const int*)d_in[1];
    const float* w1a = (const float*)d_in[2];
    const float* b1a = (const float*)d_in[3];
    const float* w1b = (const float*)d_in[4];
    const float* b1b = (const float*)d_in[5];
    const float* g1  = (const float*)d_in[6];
    const float* be1 = (const float*)d_in[7];
    const float* w2a = (const float*)d_in[8];
    const float* b2a = (const float*)d_in[9];
    const float* w2b = (const float*)d_in[10];
    const float* b2b = (const float*)d_in[11];
    const float* g2  = (const float*)d_in[12];
    const float* be2 = (const float*)d_in[13];
    const float* wl  = (const float*)d_in[14];
    const float* bl  = (const float*)d_in[15];

    float* out = (float*)d_out;

    // workspace layout (halfs)
    const size_t WN   = (size_t)FF * DD * KK;          // 1,769,472 per weight comp
    const size_t SN   = (size_t)BB * PADL * DD;        // 6,303,744
    const size_t H1N  = (size_t)BB * PADL * FF;        // 25,214,976
    _Float16* p = (_Float16*)d_ws;
    _Float16* Wh1a = p;              _Float16* Wl1a = Wh1a + WN;
    _Float16* Wh1b = Wl1a + WN;      _Float16* Wl1b = Wh1b + WN;
    _Float16* Wh2a = Wl1b + WN;      _Float16* Wl2a = Wh2a + WN;
    _Float16* Wh2b = Wl2a + WN;      _Float16* Wl2b = Wh2b + WN;
    _Float16* Shi  = Wl2b + WN;      _Float16* Slo  = Shi + SN;
    _Float16* H1hi = Slo + SN;       _Float16* H1lo = H1hi + H1N;
    int* lns  = (int*)(H1lo + H1N);
    int* csum = lns + BB * LL;

    const int M = BB * LL;                              // 16384

    // 1) weight frag-pack+split, y split, pad-zero for H1
    {
        int n = FF * DD * KK;
        wfrag_k<<<(n + 255) / 256, 256, 0, stream>>>(w1a, Wh1a, Wl1a, FF, DD);
        wfrag_k<<<(n + 255) / 256, 256, 0, stream>>>(w1b, Wh1b, Wl1b, DD, FF);
        wfrag_k<<<(n + 255) / 256, 256, 0, stream>>>(w2a, Wh2a, Wl2a, FF, DD);
        wfrag_k<<<(n + 255) / 256, 256, 0, stream>>>(w2b, Wh2b, Wl2b, DD, FF);
        int ny = BB * PADL * DD;
        ysplit_k<<<(ny + 255) / 256, 256, 0, stream>>>(y, Shi, Slo);
        int np = BB * 2 * FF;
        padzero_k<<<(np + 255) / 256, 256, 0, stream>>>(H1hi, H1lo, FF);
    }
    // 2) four conv-GEMMs (1-D grids, XCD-remapped in-kernel), MI=4/BN=96:
    //    D->F: 16n x 128m = 2048 blocks = 4.0 rounds of 512 slots (2/CU)
    //    F->D:  4n x 128m =  512 blocks = 1.0 round  of 512 slots (2/CU)
    gemm_fused<4, 96, DD, FF, 3 * DD, FF / 96>
        <<<(FF / 96) * (M / 128), 256, 0, stream>>>(Shi, Slo, Wh1a, Wl1a, b1a, H1hi, H1lo);
    gemm_fused<4, 96, FF, DD, 3 * FF, DD / 96>
        <<<(DD / 96) * (M / 128), 256, 0, stream>>>(H1hi, H1lo, Wh1b, Wl1b, b1b, Shi, Slo);
    ln_split_k<<<M, 128, 0, stream>>>(Shi, Slo, g1, be1);
    gemm_fused<4, 96, DD, FF, 3 * DD, FF / 96>
        <<<(FF / 96) * (M / 128), 256, 0, stream>>>(Shi, Slo, Wh2a, Wl2a, b2a, H1hi, H1lo);
    gemm_fused<4, 96, FF, DD, 3 * FF, DD / 96>
        <<<(DD / 96) * (M / 128), 256, 0, stream>>>(H1hi, H1lo, Wh2b, Wl2b, b2b, Shi, Slo);
    // 3) predictor + cumsum + gather
    ln_pred_split_k<<<M, 128, 0, stream>>>(Shi, Slo, g2, be2, wl, bl, tok, lns);
    cumsum_k<<<BB, 1024, 0, stream>>>(lns, csum, out + (size_t)BB * T_OUT * DD);
    {
        long long n = (long long)BB * T_OUT * 96;
        gather_k<<<(int)((n + 255) / 256), 256, 0, stream>>>(y, csum, out);
    }
}